// Round 1
// baseline (310.140 us; speedup 1.0000x reference)
//
#include <hip/hip_runtime.h>
#include <hip/hip_bf16.h>

// Problem: B=2, N=2048, D=2048, h=16, hd=128.  All dims hardcoded.
// Pipeline: cvt(x,Wqkv,Wproj)->bf16 ; rope tables ; GEMM1 qkv=x@Wqkv^T (bf16 out);
// rope+head-transpose (Q scaled by 1/sqrt(128), V transposed to (b,h,hd,n));
// flash attention (causal + key<L[b]) ; GEMM2 out = O@Wproj^T + bproj (fp32).
// Workspace ~135.3 MB with aliasing (Ob reuses xbf region, Qb reuses wqkvbf region).

typedef unsigned short u16;
typedef short bf16x8 __attribute__((ext_vector_type(8)));
typedef unsigned short u16x8 __attribute__((ext_vector_type(8)));
typedef float f32x4 __attribute__((ext_vector_type(4)));

#define MFMA16(a, b, c) __builtin_amdgcn_mfma_f32_16x16x32_bf16((a), (b), (c), 0, 0, 0)

__device__ __forceinline__ float b2f(u16 u) { return __uint_as_float(((unsigned)u) << 16); }
__device__ __forceinline__ u16 f2b(float f) {
    unsigned x = __float_as_uint(f);
    return (u16)((x + 0x7fffu + ((x >> 16) & 1u)) >> 16);
}
__device__ __forceinline__ void gload16(const u16* g, u16* lds) {
    __builtin_amdgcn_global_load_lds((__attribute__((address_space(1))) void*)g,
                                     (__attribute__((address_space(3))) void*)lds,
                                     16, 0, 0);
}

// ---------------- fp32 -> bf16 conversion (8 elems/thread, exact grids) -------------
__global__ __launch_bounds__(256) void cvt_bf16(const float* __restrict__ in,
                                                u16* __restrict__ out) {
    size_t i = (size_t)blockIdx.x * 256 + threadIdx.x;
    float4 a = ((const float4*)in)[2 * i];
    float4 b = ((const float4*)in)[2 * i + 1];
    u16x8 o;
    o[0] = f2b(a.x); o[1] = f2b(a.y); o[2] = f2b(a.z); o[3] = f2b(a.w);
    o[4] = f2b(b.x); o[5] = f2b(b.y); o[6] = f2b(b.z); o[7] = f2b(b.w);
    ((u16x8*)out)[i] = o;
}

// ---------------- RoPE tables: cos/sin[n][i], n<2048, i<64 ----------------
__global__ __launch_bounds__(256) void rope_tables_k(float* __restrict__ cosT,
                                                     float* __restrict__ sinT) {
    int idx = blockIdx.x * 256 + threadIdx.x;  // 131072 total
    int n = idx >> 6, i = idx & 63;
    float inv = powf(10000.0f, -(float)(2 * i) / 128.0f);
    float ang = (float)n * inv;
    cosT[idx] = cosf(ang);
    sinT[idx] = sinf(ang);
}

// ---------------- NT GEMM: C[M,Nc] = A[M,K] @ B[Nc,K]^T (+bias, fp32) --------------
// m97 structure: 128x128 tile, BK=32, 4 waves (2x2), global_load_lds w16, 2 barriers.
template <int OUTF32>
__global__ __launch_bounds__(256, 2) void gemm_nt(const u16* __restrict__ A,
                                                  const u16* __restrict__ B,
                                                  void* __restrict__ Cv,
                                                  const float* __restrict__ bias,
                                                  int M, int Ncols, int K) {
    __shared__ u16 As[128 * 32];
    __shared__ u16 Bs[128 * 32];
    const int tx = threadIdx.x;
    const int w = tx >> 6, l = tx & 63;
    const int fr = l & 15, fg = l >> 4;
    const int wr = w >> 1, wc = w & 1;
    const long row0 = (long)blockIdx.x * 128;
    const long col0 = (long)blockIdx.y * 128;
    f32x4 acc[4][4] = {};
    const int nk = K >> 5;
    const int c0 = tx, c1 = 256 + tx;
    const int r0 = c0 >> 2, cc0 = c0 & 3;
    const int r1 = c1 >> 2, cc1 = c1 & 3;
    for (int kt = 0; kt < nk; ++kt) {
        const long k0 = (long)kt << 5;
        __syncthreads();
        gload16(A + (row0 + r0) * K + k0 + cc0 * 8, &As[(0 * 256 + w * 64) * 8]);
        gload16(A + (row0 + r1) * K + k0 + cc1 * 8, &As[(1 * 256 + w * 64) * 8]);
        gload16(B + (col0 + r0) * K + k0 + cc0 * 8, &Bs[(0 * 256 + w * 64) * 8]);
        gload16(B + (col0 + r1) * K + k0 + cc1 * 8, &Bs[(1 * 256 + w * 64) * 8]);
        __syncthreads();
        bf16x8 af[4], bfv[4];
#pragma unroll
        for (int m = 0; m < 4; ++m)
            af[m] = *(const bf16x8*)&As[(wr * 64 + m * 16 + fr) * 32 + fg * 8];
#pragma unroll
        for (int n = 0; n < 4; ++n)
            bfv[n] = *(const bf16x8*)&Bs[(wc * 64 + n * 16 + fr) * 32 + fg * 8];
#pragma unroll
        for (int m = 0; m < 4; ++m)
#pragma unroll
            for (int n = 0; n < 4; ++n) acc[m][n] = MFMA16(af[m], bfv[n], acc[m][n]);
    }
#pragma unroll
    for (int m = 0; m < 4; ++m) {
#pragma unroll
        for (int n = 0; n < 4; ++n) {
#pragma unroll
            for (int r = 0; r < 4; ++r) {
                long row = row0 + wr * 64 + m * 16 + fg * 4 + r;
                long col = col0 + wc * 64 + n * 16 + fr;
                float v = acc[m][n][r];
                if (OUTF32) {
                    ((float*)Cv)[row * Ncols + col] = v + bias[col];
                } else {
                    ((u16*)Cv)[row * Ncols + col] = f2b(v);
                }
            }
        }
    }
}

// ---------------- RoPE apply + head transpose ----------------
// grid (N/128, B*H). Writes Q,K (b,h,n,hd) bf16 (Q scaled by 1/sqrt(hd)),
// V^T (b,h,hd,n) bf16 via LDS transpose.
__global__ __launch_bounds__(256) void rope_transpose_k(
    const u16* __restrict__ qkv, const float* __restrict__ cosT,
    const float* __restrict__ sinT, u16* __restrict__ Q, u16* __restrict__ Ko,
    u16* __restrict__ VT) {
    const int bh = blockIdx.y, b = bh >> 4, h = bh & 15;
    const int n0 = blockIdx.x << 7;
    const int tx = threadIdx.x;
    __shared__ u16 vbuf[128][136];
    const float SCALE = 0.08838834764831844f;  // 1/sqrt(128)
#pragma unroll
    for (int pass = 0; pass < 4; ++pass) {
        const int rr = pass * 32 + (tx >> 3);
        const int p = tx & 7;
        const int n = n0 + rr;
        const u16* src = qkv + ((size_t)(b * 2048 + n)) * 6144 + h * 128;
        float c[8], s[8];
#pragma unroll
        for (int j = 0; j < 8; ++j) {
            c[j] = cosT[n * 64 + p * 8 + j];
            s[j] = sinT[n * 64 + p * 8 + j];
        }
        {  // Q (scaled)
            u16x8 t1 = *(const u16x8*)&src[p * 8];
            u16x8 t2 = *(const u16x8*)&src[64 + p * 8];
            u16x8 o1, o2;
#pragma unroll
            for (int j = 0; j < 8; ++j) {
                float a = b2f(t1[j]), bb = b2f(t2[j]);
                o1[j] = f2b((a * c[j] - bb * s[j]) * SCALE);
                o2[j] = f2b((a * s[j] + bb * c[j]) * SCALE);
            }
            u16* dst = Q + ((size_t)bh * 2048 + n) * 128;
            *(u16x8*)&dst[p * 8] = o1;
            *(u16x8*)&dst[64 + p * 8] = o2;
        }
        {  // K (unscaled)
            u16x8 t1 = *(const u16x8*)&src[2048 + p * 8];
            u16x8 t2 = *(const u16x8*)&src[2048 + 64 + p * 8];
            u16x8 o1, o2;
#pragma unroll
            for (int j = 0; j < 8; ++j) {
                float a = b2f(t1[j]), bb = b2f(t2[j]);
                o1[j] = f2b(a * c[j] - bb * s[j]);
                o2[j] = f2b(a * s[j] + bb * c[j]);
            }
            u16* dst = Ko + ((size_t)bh * 2048 + n) * 128;
            *(u16x8*)&dst[p * 8] = o1;
            *(u16x8*)&dst[64 + p * 8] = o2;
        }
    }
    // V transpose: load (n,j) coalesced, write (j,n) coalesced
#pragma unroll
    for (int i = 0; i < 8; ++i) {
        int cid = i * 256 + tx;
        int rr = cid >> 4, cc = cid & 15;
        *(u16x8*)&vbuf[rr][cc * 8] =
            *(const u16x8*)&qkv[((size_t)(b * 2048 + n0 + rr)) * 6144 + 4096 + h * 128 + cc * 8];
    }
    __syncthreads();
#pragma unroll
    for (int i = 0; i < 8; ++i) {
        int cid = i * 256 + tx;
        int j = cid >> 4, nc = cid & 15;
        u16x8 o;
#pragma unroll
        for (int e = 0; e < 8; ++e) o[e] = vbuf[nc * 8 + e][j];
        *(u16x8*)&VT[((size_t)bh * 128 + j) * 2048 + n0 + nc * 8] = o;
    }
}

// ---------------- Flash attention ----------------
// grid (N/64, B*H), 4 waves x 16 q-rows. KT=64 keys/tile. K and V^T tiles staged via
// global_load_lds with XOR-swizzled SOURCE (rule 21) so ds_read_b128 frags are ~conflict-free.
__global__ __launch_bounds__(256, 2) void attn_k(const u16* __restrict__ Q,
                                                 const u16* __restrict__ K,
                                                 const u16* __restrict__ VT,
                                                 u16* __restrict__ O,
                                                 const int* __restrict__ L) {
    const int bh = blockIdx.y, b = bh >> 4, h = bh & 15;
    const int qb = blockIdx.x << 6;
    const int tx = threadIdx.x;
    const int w = tx >> 6, l = tx & 63;
    const int fr = l & 15, fg = l >> 4;
    const int Lb = L[b];
    __shared__ u16 Ks[64 * 128];   // [key][hd], chunk-swizzled: pos = hc ^ (key&7)
    __shared__ u16 Vs[128 * 64];   // [d][key],  chunk-swizzled: pos = kc ^ (d&7)
    __shared__ u16 Ps[4][16 * 72]; // per-wave P, padded rows (72) for conflict-free b128
    const u16* Qh = Q + (size_t)bh * 2048 * 128;
    const u16* Kh = K + (size_t)bh * 2048 * 128;
    const u16* Vh = VT + (size_t)bh * 128 * 2048;
    const int qrow = qb + w * 16 + fr;  // A-frag row for this lane
    bf16x8 aq[4];
#pragma unroll
    for (int kc = 0; kc < 4; ++kc)
        aq[kc] = *(const bf16x8*)&Qh[(size_t)qrow * 128 + kc * 32 + fg * 8];
    f32x4 accO[8] = {};
    float mrun[4] = {-1e30f, -1e30f, -1e30f, -1e30f};
    float srun[4] = {0.f, 0.f, 0.f, 0.f};
    const int kmax = min(qb + 63, Lb - 1);
    const int nkt = (kmax >> 6) + 1;
    for (int kt = 0; kt < nkt; ++kt) {
        const int kt0 = kt << 6;
        __syncthreads();
#pragma unroll
        for (int i = 0; i < 4; ++i) {  // K tile: 64x128 = 1024 chunks
            int c = i * 256 + tx;
            int row = c >> 4, cp = c & 15;
            gload16(Kh + (size_t)(kt0 + row) * 128 + ((cp ^ (row & 7)) << 3),
                    &Ks[(i * 256 + w * 64) * 8]);
        }
#pragma unroll
        for (int i = 0; i < 4; ++i) {  // V^T tile: 128x64 = 1024 chunks
            int c = i * 256 + tx;
            int row = c >> 3, cp = c & 7;
            gload16(Vh + (size_t)row * 2048 + kt0 + ((cp ^ (row & 7)) << 3),
                    &Vs[(i * 256 + w * 64) * 8]);
        }
        __syncthreads();
        // scores: S[16q][64k] in 4 subtiles
        f32x4 accS[4];
#pragma unroll
        for (int st = 0; st < 4; ++st) {
            f32x4 z = {0.f, 0.f, 0.f, 0.f};
            accS[st] = z;
            int key = st * 16 + fr;
#pragma unroll
            for (int kc = 0; kc < 4; ++kc) {
                bf16x8 bk = *(const bf16x8*)&Ks[key * 128 + (((kc * 4 + fg) ^ (key & 7)) << 3)];
                accS[st] = MFMA16(aq[kc], bk, accS[st]);
            }
        }
        // mask + online softmax (rows fg*4+r, 16 lanes/group hold the 16 keys of a subtile)
        float sv[4][4];
#pragma unroll
        for (int st = 0; st < 4; ++st)
#pragma unroll
            for (int r = 0; r < 4; ++r) {
                int key = kt0 + st * 16 + fr;
                int qg = qb + w * 16 + fg * 4 + r;
                float xv = accS[st][r];
                sv[st][r] = (key <= qg && key < Lb) ? xv : -1e30f;
            }
        float alpha[4], pr[4][4];
#pragma unroll
        for (int r = 0; r < 4; ++r) {
            float lm = fmaxf(fmaxf(sv[0][r], sv[1][r]), fmaxf(sv[2][r], sv[3][r]));
            lm = fmaxf(lm, __shfl_xor(lm, 1));
            lm = fmaxf(lm, __shfl_xor(lm, 2));
            lm = fmaxf(lm, __shfl_xor(lm, 4));
            lm = fmaxf(lm, __shfl_xor(lm, 8));
            float mn = fmaxf(mrun[r], lm);
            alpha[r] = exp2f((mrun[r] - mn) * 1.44269504f);
            float ls = 0.f;
#pragma unroll
            for (int st = 0; st < 4; ++st) {
                float p = exp2f((sv[st][r] - mn) * 1.44269504f);
                pr[st][r] = p;
                ls += p;
            }
            ls += __shfl_xor(ls, 1);
            ls += __shfl_xor(ls, 2);
            ls += __shfl_xor(ls, 4);
            ls += __shfl_xor(ls, 8);
            srun[r] = srun[r] * alpha[r] + ls;
            mrun[r] = mn;
        }
#pragma unroll
        for (int n = 0; n < 8; ++n)
#pragma unroll
            for (int r = 0; r < 4; ++r) accO[n][r] *= alpha[r];
        // P -> per-wave LDS (bf16)
#pragma unroll
        for (int st = 0; st < 4; ++st)
#pragma unroll
            for (int r = 0; r < 4; ++r)
                Ps[w][(fg * 4 + r) * 72 + st * 16 + fr] = f2b(pr[st][r]);
        // PV: O[16q][128d] += P[16q][64k] @ V[64k][128d]
#pragma unroll
        for (int ks = 0; ks < 2; ++ks) {
            bf16x8 ap = *(const bf16x8*)&Ps[w][fr * 72 + ks * 32 + fg * 8];
#pragma unroll
            for (int n = 0; n < 8; ++n) {
                int d = n * 16 + fr;
                bf16x8 bv = *(const bf16x8*)&Vs[d * 64 + (((ks * 4 + fg) ^ (d & 7)) << 3)];
                accO[n] = MFMA16(ap, bv, accO[n]);
            }
        }
    }
    // epilogue: normalize, write O (b, n, h*128+d) bf16
    float inv[4];
#pragma unroll
    for (int r = 0; r < 4; ++r) inv[r] = 1.0f / srun[r];
#pragma unroll
    for (int n = 0; n < 8; ++n)
#pragma unroll
        for (int r = 0; r < 4; ++r) {
            int qg = qb + w * 16 + fg * 4 + r;
            int d = n * 16 + fr;
            O[((size_t)(b * 2048 + qg)) * 2048 + h * 128 + d] = f2b(accO[n][r] * inv[r]);
        }
}

extern "C" void kernel_launch(void* const* d_in, const int* in_sizes, int n_in,
                              void* d_out, int out_size, void* d_ws, size_t ws_size,
                              hipStream_t stream) {
    const float* x = (const float*)d_in[0];
    const float* Wqkv = (const float*)d_in[1];
    const float* Wproj = (const float*)d_in[2];
    const float* bproj = (const float*)d_in[3];
    const int* L = (const int*)d_in[4];
    float* out = (float*)d_out;

    char* p = (char*)d_ws;
    // aliased layout, ~135.3 MB total
    u16* xbf = (u16*)(p + 0);                // 16.78 MB ; reused as Ob after GEMM1
    u16* wqkvbf = (u16*)(p + 16777216);      // 25.17 MB ; reused as Qb after GEMM1
    u16* wprojbf = (u16*)(p + 41943040);     // 8.39 MB
    u16* qkv = (u16*)(p + 50331648);         // 50.33 MB
    u16* Kb = (u16*)(p + 100663296);         // 16.78 MB
    u16* VTb = (u16*)(p + 117440512);        // 16.78 MB
    float* cosT = (float*)(p + 134217728);   // 0.52 MB
    float* sinT = (float*)(p + 134742016);   // 0.52 MB  (end 135,266,304)
    u16* Ob = xbf;
    u16* Qb = wqkvbf;

    cvt_bf16<<<4096, 256, 0, stream>>>(x, xbf);          // 8.39M elems
    cvt_bf16<<<6144, 256, 0, stream>>>(Wqkv, wqkvbf);    // 12.58M
    cvt_bf16<<<2048, 256, 0, stream>>>(Wproj, wprojbf);  // 4.19M
    rope_tables_k<<<512, 256, 0, stream>>>(cosT, sinT);
    gemm_nt<0><<<dim3(32, 48), 256, 0, stream>>>(xbf, wqkvbf, qkv, nullptr, 4096, 6144, 2048);
    rope_transpose_k<<<dim3(16, 32), 256, 0, stream>>>(qkv, cosT, sinT, Qb, Kb, VTb);
    attn_k<<<dim3(32, 32), 256, 0, stream>>>(Qb, Kb, VTb, Ob, L);
    gemm_nt<1><<<dim3(32, 16), 256, 0, stream>>>(Ob, wprojbf, out, bproj, 4096, 2048, 2048);
}

// Round 4
// 261.219 us; speedup vs baseline: 1.1873x; 1.1873x over previous
//
#include <hip/hip_runtime.h>
#include <hip/hip_bf16.h>

// Problem: B=2, N=2048, D=2048, h=16, hd=128.  All dims hardcoded.
// Pipeline: cvt(x,Wqkv,Wproj)->bf16 ; rope tables ; GEMM1 qkv=x@Wqkv^T (bf16, BK=64 m97-family);
// rope+head-transpose; flash attention (paired q-strips, shared K/V staging);
// GEMM2 out = O@Wproj^T + bproj (fp32, BK=64 m97-family).

typedef unsigned short u16;
typedef short bf16x8 __attribute__((ext_vector_type(8)));
typedef unsigned short u16x8 __attribute__((ext_vector_type(8)));
typedef float f32x4 __attribute__((ext_vector_type(4)));

#define MFMA16(a, b, c) __builtin_amdgcn_mfma_f32_16x16x32_bf16((a), (b), (c), 0, 0, 0)

__device__ __forceinline__ float b2f(u16 u) { return __uint_as_float(((unsigned)u) << 16); }
__device__ __forceinline__ u16 f2b(float f) {
    unsigned x = __float_as_uint(f);
    return (u16)((x + 0x7fffu + ((x >> 16) & 1u)) >> 16);
}
__device__ __forceinline__ void gload16(const u16* g, u16* lds) {
    __builtin_amdgcn_global_load_lds((__attribute__((address_space(1))) void*)g,
                                     (__attribute__((address_space(3))) void*)lds,
                                     16, 0, 0);
}

// ---------------- fp32 -> bf16 conversion (8 elems/thread, exact grids) -------------
__global__ __launch_bounds__(256) void cvt_bf16(const float* __restrict__ in,
                                                u16* __restrict__ out) {
    size_t i = (size_t)blockIdx.x * 256 + threadIdx.x;
    float4 a = ((const float4*)in)[2 * i];
    float4 b = ((const float4*)in)[2 * i + 1];
    u16x8 o;
    o[0] = f2b(a.x); o[1] = f2b(a.y); o[2] = f2b(a.z); o[3] = f2b(a.w);
    o[4] = f2b(b.x); o[5] = f2b(b.y); o[6] = f2b(b.z); o[7] = f2b(b.w);
    ((u16x8*)out)[i] = o;
}

// ---------------- RoPE tables: cos/sin[n][i], n<2048, i<64 ----------------
__global__ __launch_bounds__(256) void rope_tables_k(float* __restrict__ cosT,
                                                     float* __restrict__ sinT) {
    int idx = blockIdx.x * 256 + threadIdx.x;  // 131072 total
    int n = idx >> 6, i = idx & 63;
    float inv = powf(10000.0f, -(float)(2 * i) / 128.0f);
    float ang = (float)n * inv;
    cosT[idx] = cosf(ang);
    sinT[idx] = sinf(ang);
}

// ---------------- NT GEMM: C[M,Nc] = A[M,K] @ B[Nc,K]^T (+bias, fp32) --------------
// m97-family: 128x128 tile, BK=64, 4 waves (2x2), global_load_lds w16, 2 barriers/K-step.
// BK=64 linear LDS rows would be a 16-way read conflict -> XOR involution on chunk-col:
// staged SOURCE chunk = slot ^ (row&7) (linear LDS dest, rule 21); frag READ applies the
// same XOR. 32 MFMA per barrier pair (2x the BK=32 amortization of the drain stall).
template <int OUTF32>
__global__ __launch_bounds__(256, 2) void gemm_nt(const u16* __restrict__ A,
                                                  const u16* __restrict__ B,
                                                  void* __restrict__ Cv,
                                                  const float* __restrict__ bias,
                                                  int M, int Ncols, int K) {
    __shared__ u16 As[128 * 64];
    __shared__ u16 Bs[128 * 64];
    const int tx = threadIdx.x;
    const int w = tx >> 6, l = tx & 63;
    const int fr = l & 15, fg = l >> 4;
    const int wr = w >> 1, wc = w & 1;
    const long row0 = (long)blockIdx.x * 128;
    const long col0 = (long)blockIdx.y * 128;
    f32x4 acc[4][4] = {};
    const int nk = K >> 6;
    int rs[4], ss[4];
#pragma unroll
    for (int i = 0; i < 4; ++i) {
        int c = i * 256 + tx;
        rs[i] = c >> 3;
        ss[i] = (c & 7) ^ ((c >> 3) & 7);
    }
    for (int kt = 0; kt < nk; ++kt) {
        const long k0 = (long)kt << 6;
        __syncthreads();
#pragma unroll
        for (int i = 0; i < 4; ++i)
            gload16(A + (row0 + rs[i]) * K + k0 + ss[i] * 8, &As[(i * 256 + w * 64) * 8]);
#pragma unroll
        for (int i = 0; i < 4; ++i)
            gload16(B + (col0 + rs[i]) * K + k0 + ss[i] * 8, &Bs[(i * 256 + w * 64) * 8]);
        __syncthreads();
#pragma unroll
        for (int kk = 0; kk < 2; ++kk) {
            bf16x8 af[4], bfv[4];
#pragma unroll
            for (int m = 0; m < 4; ++m) {
                int r = wr * 64 + m * 16 + fr;
                af[m] = *(const bf16x8*)&As[r * 64 + (((kk * 4 + fg) ^ (r & 7)) << 3)];
            }
#pragma unroll
            for (int n = 0; n < 4; ++n) {
                int r = wc * 64 + n * 16 + fr;
                bfv[n] = *(const bf16x8*)&Bs[r * 64 + (((kk * 4 + fg) ^ (r & 7)) << 3)];
            }
#pragma unroll
            for (int m = 0; m < 4; ++m)
#pragma unroll
                for (int n = 0; n < 4; ++n) acc[m][n] = MFMA16(af[m], bfv[n], acc[m][n]);
        }
    }
#pragma unroll
    for (int m = 0; m < 4; ++m) {
#pragma unroll
        for (int n = 0; n < 4; ++n) {
#pragma unroll
            for (int r = 0; r < 4; ++r) {
                long row = row0 + wr * 64 + m * 16 + fg * 4 + r;
                long col = col0 + wc * 64 + n * 16 + fr;
                float v = acc[m][n][r];
                if (OUTF32) {
                    ((float*)Cv)[row * Ncols + col] = v + bias[col];
                } else {
                    ((u16*)Cv)[row * Ncols + col] = f2b(v);
                }
            }
        }
    }
}

// ---------------- RoPE apply + head transpose ----------------
__global__ __launch_bounds__(256) void rope_transpose_k(
    const u16* __restrict__ qkv, const float* __restrict__ cosT,
    const float* __restrict__ sinT, u16* __restrict__ Q, u16* __restrict__ Ko,
    u16* __restrict__ VT) {
    const int bh = blockIdx.y, b = bh >> 4, h = bh & 15;
    const int n0 = blockIdx.x << 7;
    const int tx = threadIdx.x;
    __shared__ u16 vbuf[128][136];
    const float SCALE = 0.08838834764831844f;  // 1/sqrt(128)
#pragma unroll
    for (int pass = 0; pass < 4; ++pass) {
        const int rr = pass * 32 + (tx >> 3);
        const int p = tx & 7;
        const int n = n0 + rr;
        const u16* src = qkv + ((size_t)(b * 2048 + n)) * 6144 + h * 128;
        float c[8], s[8];
#pragma unroll
        for (int j = 0; j < 8; ++j) {
            c[j] = cosT[n * 64 + p * 8 + j];
            s[j] = sinT[n * 64 + p * 8 + j];
        }
        {  // Q (scaled)
            u16x8 t1 = *(const u16x8*)&src[p * 8];
            u16x8 t2 = *(const u16x8*)&src[64 + p * 8];
            u16x8 o1, o2;
#pragma unroll
            for (int j = 0; j < 8; ++j) {
                float a = b2f(t1[j]), bb = b2f(t2[j]);
                o1[j] = f2b((a * c[j] - bb * s[j]) * SCALE);
                o2[j] = f2b((a * s[j] + bb * c[j]) * SCALE);
            }
            u16* dst = Q + ((size_t)bh * 2048 + n) * 128;
            *(u16x8*)&dst[p * 8] = o1;
            *(u16x8*)&dst[64 + p * 8] = o2;
        }
        {  // K (unscaled)
            u16x8 t1 = *(const u16x8*)&src[2048 + p * 8];
            u16x8 t2 = *(const u16x8*)&src[2048 + 64 + p * 8];
            u16x8 o1, o2;
#pragma unroll
            for (int j = 0; j < 8; ++j) {
                float a = b2f(t1[j]), bb = b2f(t2[j]);
                o1[j] = f2b(a * c[j] - bb * s[j]);
                o2[j] = f2b(a * s[j] + bb * c[j]);
            }
            u16* dst = Ko + ((size_t)bh * 2048 + n) * 128;
            *(u16x8*)&dst[p * 8] = o1;
            *(u16x8*)&dst[64 + p * 8] = o2;
        }
    }
    // V transpose
#pragma unroll
    for (int i = 0; i < 8; ++i) {
        int cid = i * 256 + tx;
        int rr = cid >> 4, cc = cid & 15;
        *(u16x8*)&vbuf[rr][cc * 8] =
            *(const u16x8*)&qkv[((size_t)(b * 2048 + n0 + rr)) * 6144 + 4096 + h * 128 + cc * 8];
    }
    __syncthreads();
#pragma unroll
    for (int i = 0; i < 8; ++i) {
        int cid = i * 256 + tx;
        int j = cid >> 4, nc = cid & 15;
        u16x8 o;
#pragma unroll
        for (int e = 0; e < 8; ++e) o[e] = vbuf[nc * 8 + e][j];
        *(u16x8*)&VT[((size_t)bh * 128 + j) * 2048 + n0 + nc * 8] = o;
    }
}

// ---------------- Flash attention (paired q-strips) ----------------
// grid (16, B*H).  Block qx handles q-strips {qx*64, (31-qx)*64}: per-block work is
// ~constant (33 tiles) -> perfect load balance at 512 blocks = 2/CU, and each staged
// K/V tile serves both strips (2x reuse).  Low strip computes only while kt <= qx
// (wave-uniform branch).  4 waves x 16 q-rows per strip.  KT=64 keys/tile.
// NOTE: do_strip's qgb is the strip row base + w*16 ONLY; fg*4+r added inside (the
// round-3 bug was double-adding fg*4).
__global__ __launch_bounds__(256, 2) void attn_k(const u16* __restrict__ Q,
                                                 const u16* __restrict__ K,
                                                 const u16* __restrict__ VT,
                                                 u16* __restrict__ O,
                                                 const int* __restrict__ L) {
    const int bh = blockIdx.y, b = bh >> 4, h = bh & 15;
    const int qx = blockIdx.x;
    const int qb0 = qx << 6, qb1 = (31 - qx) << 6;
    const int tx = threadIdx.x;
    const int w = tx >> 6, l = tx & 63;
    const int fr = l & 15, fg = l >> 4;
    const int Lb = L[b];
    __shared__ u16 Ks[64 * 128];   // [key][hd], chunk-swizzled: slot = cp ^ (key&7)
    __shared__ u16 Vs[128 * 64];   // [d][key],  chunk-swizzled: slot = kc ^ (d&7)
    __shared__ u16 Ps[4][16 * 72]; // per-wave P, padded rows (72) for conflict-free b128
    const u16* Qh = Q + (size_t)bh * 2048 * 128;
    const u16* Kh = K + (size_t)bh * 2048 * 128;
    const u16* Vh = VT + (size_t)bh * 128 * 2048;
    bf16x8 aq0[4], aq1[4];
#pragma unroll
    for (int kc = 0; kc < 4; ++kc) {
        aq0[kc] = *(const bf16x8*)&Qh[(size_t)(qb0 + w * 16 + fr) * 128 + kc * 32 + fg * 8];
        aq1[kc] = *(const bf16x8*)&Qh[(size_t)(qb1 + w * 16 + fr) * 128 + kc * 32 + fg * 8];
    }
    f32x4 accO0[8] = {}, accO1[8] = {};
    float mr0[4] = {-1e30f, -1e30f, -1e30f, -1e30f};
    float mr1[4] = {-1e30f, -1e30f, -1e30f, -1e30f};
    float sr0[4] = {0.f, 0.f, 0.f, 0.f};
    float sr1[4] = {0.f, 0.f, 0.f, 0.f};
    const int kmax = min(qb1 + 63, Lb - 1);
    const int nkt = (kmax >> 6) + 1;

    auto do_strip = [&](const bf16x8 (&aqs)[4], float (&mr)[4], float (&sr)[4],
                        f32x4 (&aO)[8], int qgb, int kt0) {
        f32x4 accS[4];
#pragma unroll
        for (int st = 0; st < 4; ++st) {
            f32x4 z = {0.f, 0.f, 0.f, 0.f};
            accS[st] = z;
            int key = st * 16 + fr;
#pragma unroll
            for (int kc = 0; kc < 4; ++kc) {
                bf16x8 bk = *(const bf16x8*)&Ks[key * 128 + (((kc * 4 + fg) ^ (key & 7)) << 3)];
                accS[st] = MFMA16(aqs[kc], bk, accS[st]);
            }
        }
        float sv[4][4];
#pragma unroll
        for (int st = 0; st < 4; ++st)
#pragma unroll
            for (int r = 0; r < 4; ++r) {
                int key = kt0 + st * 16 + fr;
                int qg = qgb + fg * 4 + r;
                sv[st][r] = (key <= qg && key < Lb) ? accS[st][r] : -1e30f;
            }
        float alpha[4], pr[4][4];
#pragma unroll
        for (int r = 0; r < 4; ++r) {
            float lm = fmaxf(fmaxf(sv[0][r], sv[1][r]), fmaxf(sv[2][r], sv[3][r]));
            lm = fmaxf(lm, __shfl_xor(lm, 1));
            lm = fmaxf(lm, __shfl_xor(lm, 2));
            lm = fmaxf(lm, __shfl_xor(lm, 4));
            lm = fmaxf(lm, __shfl_xor(lm, 8));
            float mn = fmaxf(mr[r], lm);
            alpha[r] = exp2f((mr[r] - mn) * 1.44269504f);
            float ls = 0.f;
#pragma unroll
            for (int st = 0; st < 4; ++st) {
                float p = exp2f((sv[st][r] - mn) * 1.44269504f);
                pr[st][r] = p;
                ls += p;
            }
            ls += __shfl_xor(ls, 1);
            ls += __shfl_xor(ls, 2);
            ls += __shfl_xor(ls, 4);
            ls += __shfl_xor(ls, 8);
            sr[r] = sr[r] * alpha[r] + ls;
            mr[r] = mn;
        }
#pragma unroll
        for (int n = 0; n < 8; ++n)
#pragma unroll
            for (int r = 0; r < 4; ++r) aO[n][r] *= alpha[r];
#pragma unroll
        for (int st = 0; st < 4; ++st)
#pragma unroll
            for (int r = 0; r < 4; ++r)
                Ps[w][(fg * 4 + r) * 72 + st * 16 + fr] = f2b(pr[st][r]);
#pragma unroll
        for (int ks = 0; ks < 2; ++ks) {
            bf16x8 ap = *(const bf16x8*)&Ps[w][fr * 72 + ks * 32 + fg * 8];
#pragma unroll
            for (int n = 0; n < 8; ++n) {
                int d = n * 16 + fr;
                bf16x8 bv = *(const bf16x8*)&Vs[d * 64 + (((ks * 4 + fg) ^ (d & 7)) << 3)];
                aO[n] = MFMA16(ap, bv, aO[n]);
            }
        }
    };

    for (int kt = 0; kt < nkt; ++kt) {
        const int kt0 = kt << 6;
        __syncthreads();
#pragma unroll
        for (int i = 0; i < 4; ++i) {  // K tile: 64x128 = 1024 chunks
            int c = i * 256 + tx;
            int row = c >> 4, cp = c & 15;
            gload16(Kh + (size_t)(kt0 + row) * 128 + ((cp ^ (row & 7)) << 3),
                    &Ks[(i * 256 + w * 64) * 8]);
        }
#pragma unroll
        for (int i = 0; i < 4; ++i) {  // V^T tile: 128x64 = 1024 chunks
            int c = i * 256 + tx;
            int row = c >> 3, cp = c & 7;
            gload16(Vh + (size_t)row * 2048 + kt0 + ((cp ^ (row & 7)) << 3),
                    &Vs[(i * 256 + w * 64) * 8]);
        }
        __syncthreads();
        if (kt <= qx)  // low strip's causal bound (wave-uniform)
            do_strip(aq0, mr0, sr0, accO0, qb0 + w * 16, kt0);
        do_strip(aq1, mr1, sr1, accO1, qb1 + w * 16, kt0);
    }
    float inv0[4], inv1[4];
#pragma unroll
    for (int r = 0; r < 4; ++r) {
        inv0[r] = 1.0f / sr0[r];
        inv1[r] = 1.0f / sr1[r];
    }
#pragma unroll
    for (int n = 0; n < 8; ++n)
#pragma unroll
        for (int r = 0; r < 4; ++r) {
            int d = n * 16 + fr;
            int q0 = qb0 + w * 16 + fg * 4 + r;
            int q1 = qb1 + w * 16 + fg * 4 + r;
            O[((size_t)(b * 2048 + q0)) * 2048 + h * 128 + d] = f2b(accO0[n][r] * inv0[r]);
            O[((size_t)(b * 2048 + q1)) * 2048 + h * 128 + d] = f2b(accO1[n][r] * inv1[r]);
        }
}

extern "C" void kernel_launch(void* const* d_in, const int* in_sizes, int n_in,
                              void* d_out, int out_size, void* d_ws, size_t ws_size,
                              hipStream_t stream) {
    const float* x = (const float*)d_in[0];
    const float* Wqkv = (const float*)d_in[1];
    const float* Wproj = (const float*)d_in[2];
    const float* bproj = (const float*)d_in[3];
    const int* L = (const int*)d_in[4];
    float* out = (float*)d_out;

    char* p = (char*)d_ws;
    u16* xbf = (u16*)(p + 0);                // reused as Ob after GEMM1
    u16* wqkvbf = (u16*)(p + 16777216);      // reused as Qb after GEMM1
    u16* wprojbf = (u16*)(p + 41943040);
    u16* qkv = (u16*)(p + 50331648);
    u16* Kb = (u16*)(p + 100663296);
    u16* VTb = (u16*)(p + 117440512);
    float* cosT = (float*)(p + 134217728);
    float* sinT = (float*)(p + 134742016);
    u16* Ob = xbf;
    u16* Qb = wqkvbf;

    cvt_bf16<<<4096, 256, 0, stream>>>(x, xbf);
    cvt_bf16<<<6144, 256, 0, stream>>>(Wqkv, wqkvbf);
    cvt_bf16<<<2048, 256, 0, stream>>>(Wproj, wprojbf);
    rope_tables_k<<<512, 256, 0, stream>>>(cosT, sinT);
    gemm_nt<0><<<dim3(32, 48), 256, 0, stream>>>(xbf, wqkvbf, qkv, nullptr, 4096, 6144, 2048);
    rope_transpose_k<<<dim3(16, 32), 256, 0, stream>>>(qkv, cosT, sinT, Qb, Kb, VTb);
    attn_k<<<dim3(16, 32), 256, 0, stream>>>(Qb, Kb, VTb, Ob, L);
    gemm_nt<1><<<dim3(32, 16), 256, 0, stream>>>(Ob, wprojbf, out, bproj, 4096, 2048, 2048);
}